// Round 20
// baseline (5894.680 us; speedup 1.0000x reference)
//
#include <hip/hip_runtime.h>

typedef unsigned int u32;
typedef unsigned short u16;

// problem sizes
#define BB 16
#define NN 2048
#define KK 20
#define EE (BB*NN*KK)      // 655360 edges
#define PP (BB*NN)         // 32768 points
#define NCHK 8             // kNN candidate chunks
#define CHKSZ (NN/NCHK)    // 256 candidates per chunk

// output element offsets (fp32 elements, tuple flattened in return order)
#define O_XPER 0
#define O_XCUB 3932160
#define O_Z    3962880
#define O_MU   3966976
#define O_LV   3971072
#define O_ASG  3975168

// ---- static device scratch: all write-before-read each call, no atomics ----
__device__ double g_part[4096*128];           // stats partials / kNN counters (4 MB)
__device__ float  g_st[2560];                 // BN A/B per stage + stage3 A/B
__device__ float  g_gsf[BB*1024];             // global max g (B,1024)
__device__ float  g_zf[BB*256];               // z
__device__ float  g_Kf[BB*1024];              // Kf (B,64,16)
__device__ u16    g_idx[EE];                  // kNN indices
__device__ float  g_xpf[(size_t)PP*120];      // point-major x_per mirror (15.7 MB)
__device__ float  g_e1[(size_t)EE*60];        // knn tops -> y1b -> y2a -> y3
__device__ float  g_e2[(size_t)EE*60];        // knn T -> y1a -> U/V -> y2b

// A/B bases in g_st: per 60-ch stage {A@+0, B@+64}
#define S1A_AB 0
#define S1B_AB 128
#define S2A_AB 256
#define S2B_AB 384
#define S3A 512
#define S3B 1536

#define NEG_BIG -1.0e30f

__device__ __forceinline__ float lrelu(float x){ return x > 0.f ? x : 0.2f*x; }

__device__ __forceinline__ void xrow(int bn, int c0, int cnt, float* d){
  const float* s = g_xpf + (size_t)bn*120 + c0;
  #pragma unroll 4
  for (int i=0;i<cnt;i+=4){
    float4 v = *(const float4*)(s+i);
    d[i]=v.x; d[i+1]=v.y; d[i+2]=v.z; d[i+3]=v.w;
  }
}

// shared pd computation: MUST be bit-identical across all kNN kernels
__device__ __forceinline__ float pdcalc(float4 pm, float qx, float qy, float qz, float qw){
  float dot = fmaf(qx,pm.x, fmaf(qy,pm.y, qz*pm.z));
  float t = fmaf(2.f, dot, -qw);
  return t - pm.w;                      // == -||q-p||^2
}

// ---- float-only top-20 chain (distances only; 2 VALU ops per stage)
#define KT_DECL \
  float td0=NEG_BIG,td1=NEG_BIG,td2=NEG_BIG,td3=NEG_BIG,td4=NEG_BIG, \
        td5=NEG_BIG,td6=NEG_BIG,td7=NEG_BIG,td8=NEG_BIG,td9=NEG_BIG, \
        td10=NEG_BIG,td11=NEG_BIG,td12=NEG_BIG,td13=NEG_BIG,td14=NEG_BIG, \
        td15=NEG_BIG,td16=NEG_BIG,td17=NEG_BIG,td18=NEG_BIG,td19=NEG_BIG;
#define KT_CSW(u,l) { float mx = fmaxf(td##u, td##l); float mn = fminf(td##u, td##l); td##u = mx; td##l = mn; }
#define KT_INSERT(pd) \
  if ((pd) > td19){ \
    td19 = (pd); \
    KT_CSW(18,19) KT_CSW(17,18) KT_CSW(16,17) KT_CSW(15,16) \
    KT_CSW(14,15) KT_CSW(13,14) KT_CSW(12,13) KT_CSW(11,12) \
    KT_CSW(10,11) KT_CSW(9,10)  KT_CSW(8,9)   KT_CSW(7,8)   \
    KT_CSW(6,7)   KT_CSW(5,6)   KT_CSW(4,5)   KT_CSW(3,4)   \
    KT_CSW(2,3)   KT_CSW(1,2)   KT_CSW(0,1) }

// ---------------- kNN pass 1
__global__ __launch_bounds__(128) void k_knnt(const float* __restrict__ xyz){
  __shared__ float4 cand[CHKSZ];
  int qg = blockIdx.x >> 3;
  int c  = blockIdx.x & 7;
  int b  = qg >> 4;
  int n0 = (qg & 15) << 7;
  int t  = threadIdx.x;
  int m0 = c*CHKSZ;
  for (int i=t;i<CHKSZ;i+=128){
    const float* s = xyz + ((size_t)((b<<11)+m0+i))*3;
    float x=s[0], y=s[1], z=s[2];
    cand[i] = make_float4(x,y,z, fmaf(x,x,fmaf(y,y,z*z)));
  }
  __syncthreads();
  int n = n0 + t;
  const float* qs = xyz + ((size_t)((b<<11)+n))*3;
  float qx=qs[0], qy=qs[1], qz=qs[2];
  float qw = fmaf(qx,qx,fmaf(qy,qy,qz*qz));
  KT_DECL
  for (int i=0;i<CHKSZ;i++){
    float pd = pdcalc(cand[i], qx,qy,qz,qw);
    KT_INSERT(pd)
  }
  int p = (b<<11) + n;
  float* outd = g_e1;
  #define KOUT(k) outd[(size_t)(c*KK+k)*PP + p] = td##k;
  KOUT(0) KOUT(1) KOUT(2) KOUT(3) KOUT(4) KOUT(5) KOUT(6) KOUT(7) KOUT(8) KOUT(9)
  KOUT(10) KOUT(11) KOUT(12) KOUT(13) KOUT(14) KOUT(15) KOUT(16) KOUT(17) KOUT(18) KOUT(19)
  #undef KOUT
}

// ---------------- kNN pass 2: exact 20th-largest threshold T[q]
__global__ __launch_bounds__(256) void k_knnu(){
  int q = blockIdx.x*256 + threadIdx.x;
  const float* ind = g_e1;
  KT_DECL
  for (int i=0;i<NCHK*KK;i++){
    float pd = ind[(size_t)i*PP + q];
    KT_INSERT(pd)
  }
  g_e2[q] = td19;
}

// ---------------- kNN pass 3: count pd>T, pd==T per (query, chunk)
__global__ __launch_bounds__(256) void k_knns1(const float* __restrict__ xyz){
  __shared__ float4 cand[CHKSZ];
  int gid = blockIdx.x*256 + threadIdx.x;
  int c = gid >> 15;
  int q = gid & (PP-1);
  int b = q >> 11;
  int t = threadIdx.x;
  for (int i=t;i<CHKSZ;i+=256){
    const float* s = xyz + ((size_t)((b<<11)+c*CHKSZ+i))*3;
    float x=s[0], y=s[1], z=s[2];
    cand[i] = make_float4(x,y,z, fmaf(x,x,fmaf(y,y,z*z)));
  }
  __syncthreads();
  const float* qs = xyz + (size_t)q*3;
  float qx=qs[0], qy=qs[1], qz=qs[2];
  float qw = fmaf(qx,qx,fmaf(qy,qy,qz*qz));
  float T = g_e2[q];
  u32 cgt=0, ceq=0;
  for (int i=0;i<CHKSZ;i++){
    float pd = pdcalc(cand[i], qx,qy,qz,qw);
    cgt += (pd > T) ? 1u : 0u;
    ceq += (pd == T) ? 1u : 0u;
  }
  u32* cntg = (u32*)g_part;
  u32* cnte = cntg + NCHK*PP;
  cntg[c*PP + q] = cgt;
  cnte[c*PP + q] = ceq;
}

// ---------------- kNN pass 4: prefix over chunks
__global__ __launch_bounds__(256) void k_knns2(){
  int q = blockIdx.x*256 + threadIdx.x;
  u32* cntg = (u32*)g_part;
  u32* cnte = cntg + NCHK*PP;
  u32* bg   = cnte + NCHK*PP;
  u32* be   = bg   + NCHK*PP;
  u32 acc = 0;
  for (int c=0;c<NCHK;c++){ bg[c*PP+q] = acc; acc += cntg[c*PP+q]; }
  u32 eacc = acc;
  for (int c=0;c<NCHK;c++){ be[c*PP+q] = eacc; eacc += cnte[c*PP+q]; }
}

// ---------------- kNN pass 5: write indices
__global__ __launch_bounds__(256) void k_knns3(const float* __restrict__ xyz){
  __shared__ float4 cand[CHKSZ];
  int gid = blockIdx.x*256 + threadIdx.x;
  int c = gid >> 15;
  int q = gid & (PP-1);
  int b = q >> 11;
  int t = threadIdx.x;
  for (int i=t;i<CHKSZ;i+=256){
    const float* s = xyz + ((size_t)((b<<11)+c*CHKSZ+i))*3;
    float x=s[0], y=s[1], z=s[2];
    cand[i] = make_float4(x,y,z, fmaf(x,x,fmaf(y,y,z*z)));
  }
  __syncthreads();
  const float* qs = xyz + (size_t)q*3;
  float qx=qs[0], qy=qs[1], qz=qs[2];
  float qw = fmaf(qx,qx,fmaf(qy,qy,qz*qz));
  float T = g_e2[q];
  const u32* cntg = (const u32*)g_part;
  const u32* cnte = cntg + NCHK*PP;
  const u32* bg   = cnte + NCHK*PP;
  const u32* be   = bg   + NCHK*PP;
  u32 wgt = bg[c*PP+q];
  u32 weq = be[c*PP+q];
  u16* o = g_idx + (size_t)q*KK;
  for (int i=0;i<CHKSZ;i++){
    float pd = pdcalc(cand[i], qx,qy,qz,qw);
    int m = c*CHKSZ + i;
    if (pd > T && wgt < KK){ o[wgt] = (u16)m; wgt++; }
    else if (pd == T && weq < KK){ o[weq] = (u16)m; weq++; }
  }
}

// ---------------- generic streaming sum/sumsq over g_e1 (sel=0) or g_e2 (sel=1)
__global__ __launch_bounds__(256) void k_sstat(int sel, int cpc, int chunk_len){
  __shared__ double rs[256], rq[256];
  const float* buf = sel ? g_e2 : g_e1;
  int chan = blockIdx.x / cpc;
  int chunk = blockIdx.x % cpc;
  size_t base = (size_t)chan*((size_t)cpc*chunk_len) + (size_t)chunk*chunk_len;
  int t = threadIdx.x;
  double s = 0.0, q = 0.0;
  const float4* b4 = (const float4*)(buf + base);
  int n4 = chunk_len >> 2;
  for (int i=t;i<n4;i+=256){
    float4 v = b4[i];
    s += (double)v.x + (double)v.y + (double)v.z + (double)v.w;
    q += (double)v.x*v.x + (double)v.y*v.y + (double)v.z*v.z + (double)v.w*v.w;
  }
  rs[t]=s; rq[t]=q; __syncthreads();
  for (int w=128;w>0;w>>=1){ if (t<w){ rs[t]+=rs[t+w]; rq[t]+=rq[t+w]; } __syncthreads(); }
  if (t==0){ g_part[blockIdx.x*2] = rs[0]; g_part[blockIdx.x*2+1] = rq[0]; }
}

// finalize 60-ch stage from cpc partial pairs per channel
__global__ __launch_bounds__(64) void k_finS(const float* __restrict__ g, const float* __restrict__ bb,
                                             int abase, int cpc, double invc){
  int c = threadIdx.x;
  if (c < 60){
    double s=0.0, q=0.0;
    for (int j=0;j<cpc;j++){ s += g_part[(c*cpc+j)*2]; q += g_part[(c*cpc+j)*2+1]; }
    double m = s*invc;
    double v = q*invc - m*m;
    if (v < 0.0) v = 0.0;
    float r = (float)(1.0/sqrt(v + 1e-5));
    float a = r*g[c];
    g_st[abase+c] = a;
    g_st[abase+64+c] = bb[c] - (float)m*a;
  }
}
// finalize 1024-ch stage3 (cpc=4)
__global__ __launch_bounds__(64) void k_fin3S(const float* __restrict__ g, const float* __restrict__ bb, double invc){
  int c = blockIdx.x*64 + threadIdx.x;
  double s=0.0, q=0.0;
  for (int j=0;j<4;j++){ s += g_part[(c*4+j)*2]; q += g_part[(c*4+j)*2+1]; }
  double m = s*invc;
  double v = q*invc - m*m;
  if (v < 0.0) v = 0.0;
  float r = (float)(1.0/sqrt(v + 1e-5));
  float a = r*g[c];
  g_st[S3A+c] = a;
  g_st[S3B+c] = bb[c] - (float)m*a;
}

// ==== stage1 conv-a PURE: y1a -> g_e2 channel-major ====
__global__ __launch_bounds__(256) void k_conv1a(const float* __restrict__ xyz, const float* __restrict__ w1a){
  __shared__ float ws[360];
  int tid = threadIdx.x;
  for (int i=tid;i<360;i+=256) ws[i]=w1a[i];
  __syncthreads();
  int edge = blockIdx.x*256 + tid;
  int row = edge / KK;
  int b = row >> 11;
  int nbr = g_idx[edge];
  const float* cp = xyz + (size_t)row*3;
  const float* np2 = xyz + ((size_t)((b<<11)+nbr))*3;
  float c0=cp[0], c1=cp[1], c2=cp[2];
  float d0=np2[0]-c0, d1=np2[1]-c1, d2=np2[2]-c2;
  #pragma unroll
  for (int o=0;o<60;o++){
    float y = ws[o*6]*d0 + ws[o*6+1]*d1 + ws[o*6+2]*d2 + ws[o*6+3]*c0 + ws[o*6+4]*c1 + ws[o*6+5]*c2;
    g_e2[(size_t)o*EE + edge] = y;
  }
}

// ==== stage1 conv-b PURE: h=lrelu(affine(y1a)); y1b=w1b.h -> g_e1 ====
__global__ __launch_bounds__(256) void k_conv1b(const float* __restrict__ w1b){
  __shared__ float wbs[3600];
  __shared__ float As[60], Bs[60];
  int tid = threadIdx.x;
  for (int i=tid;i<3600;i+=256) wbs[i]=w1b[i];
  if (tid<60){ As[tid]=g_st[S1A_AB+tid]; Bs[tid]=g_st[S1A_AB+64+tid]; }
  __syncthreads();
  int edge = blockIdx.x*256 + tid;
  float h[60];
  #pragma unroll 4
  for (int o=0;o<60;o++) h[o] = lrelu(fmaf(As[o], g_e2[(size_t)o*EE + edge], Bs[o]));
  #pragma unroll
  for (int o=0;o<60;o++){
    float y=0.f;
    #pragma unroll
    for (int c=0;c<60;c++) y = fmaf(wbs[o*60+c], h[c], y);
    g_e1[(size_t)o*EE + edge] = y;
  }
}

// ==== stage1 final: x1 from g_e1 ====
__global__ __launch_bounds__(256) void k_final1s(float* __restrict__ outb){
  int o = blockIdx.x >> 7;
  int bn = ((blockIdx.x & 127) << 8) + threadIdx.x;
  int b = bn >> 11, n = bn & 2047;
  float A = g_st[S1B_AB+o], Bv = g_st[S1B_AB+64+o];
  const float* src = g_e1 + (size_t)o*EE + (size_t)bn*KK;
  float mx = NEG_BIG;
  #pragma unroll
  for (int k=0;k<KK;k++) mx = fmaxf(mx, lrelu(fmaf(A, src[k], Bv)));
  g_xpf[(size_t)bn*120 + o] = mx;
  outb[O_XPER + (size_t)(b*120+o)*NN + n] = mx;
}

// ==== stage2 point transforms: U = Wd.x1, V = (Wc-Wd).x1 -> g_e2 [p][64] ====
__global__ __launch_bounds__(256) void k_pgem2(const float* __restrict__ w2a){
  __shared__ float wd[3600], wcd[3600];
  int tid = threadIdx.x;
  for (int i=tid;i<3600;i+=256){
    int o = i/60, c = i%60;
    float a = w2a[o*120+c], bvl = w2a[o*120+60+c];
    wd[i] = a; wcd[i] = bvl - a;
  }
  __syncthreads();
  int p = blockIdx.x*256 + tid;
  float x[60];
  xrow(p, 0, 60, x);
  float* gU = g_e2;
  float* gV = g_e2 + (size_t)PP*64;
  #pragma unroll 4
  for (int o=0;o<60;o++){
    float u=0.f, v=0.f;
    #pragma unroll
    for (int c=0;c<60;c++){ u = fmaf(wd[o*60+c], x[c], u); v = fmaf(wcd[o*60+c], x[c], v); }
    gU[(size_t)p*64 + o] = u;
    gV[(size_t)p*64 + o] = v;
  }
}

// ==== stage2 conv-a PURE: y2a = U[nbr] + V[center] -> g_e1 ====
__global__ __launch_bounds__(256) void k_conv2a(){
  int tid = threadIdx.x;
  int edge = blockIdx.x*256 + tid;
  int row = edge / KK;
  int b = row >> 11;
  int nbr = g_idx[edge];
  int pn = (b<<11)+nbr;
  const float4* gU = (const float4*)g_e2;
  const float4* gV = (const float4*)(g_e2 + (size_t)PP*64);
  #pragma unroll
  for (int o4=0;o4<15;o4++){
    float4 uu = gU[(size_t)pn*16 + o4];
    float4 vv = gV[(size_t)row*16 + o4];
    g_e1[(size_t)(o4*4+0)*EE + edge] = uu.x+vv.x;
    g_e1[(size_t)(o4*4+1)*EE + edge] = uu.y+vv.y;
    g_e1[(size_t)(o4*4+2)*EE + edge] = uu.z+vv.z;
    g_e1[(size_t)(o4*4+3)*EE + edge] = uu.w+vv.w;
  }
}

// ==== stage2 conv-b PURE: h=lrelu(affine(y2a)); y2b=w2b.h -> g_e2 (after U/V dead) ====
__global__ __launch_bounds__(256) void k_conv2b(const float* __restrict__ w2b){
  __shared__ float wbs[3600];
  __shared__ float As[60], Bs[60];
  int tid = threadIdx.x;
  for (int i=tid;i<3600;i+=256) wbs[i]=w2b[i];
  if (tid<60){ As[tid]=g_st[S2A_AB+tid]; Bs[tid]=g_st[S2A_AB+64+tid]; }
  __syncthreads();
  int edge = blockIdx.x*256 + tid;
  float h[60];
  #pragma unroll 4
  for (int o=0;o<60;o++) h[o] = lrelu(fmaf(As[o], g_e1[(size_t)o*EE + edge], Bs[o]));
  #pragma unroll
  for (int o=0;o<60;o++){
    float y=0.f;
    #pragma unroll
    for (int c=0;c<60;c++) y = fmaf(wbs[o*60+c], h[c], y);
    g_e2[(size_t)o*EE + edge] = y;
  }
}

// ==== stage2 final: x2 from g_e2 ====
__global__ __launch_bounds__(256) void k_final2s(float* __restrict__ outb){
  int o = blockIdx.x >> 7;
  int bn = ((blockIdx.x & 127) << 8) + threadIdx.x;
  int b = bn >> 11, n = bn & 2047;
  float A = g_st[S2B_AB+o], Bv = g_st[S2B_AB+64+o];
  const float* src = g_e2 + (size_t)o*EE + (size_t)bn*KK;
  float mx = NEG_BIG;
  #pragma unroll
  for (int k=0;k<KK;k++) mx = fmaxf(mx, lrelu(fmaf(A, src[k], Bv)));
  g_xpf[(size_t)bn*120 + 60 + o] = mx;
  outb[O_XPER + (size_t)(b*120+60+o)*NN + n] = mx;
}

// ==== c3 PURE: y3[e][point] -> g_e1 ====
__global__ __launch_bounds__(256) void k_conv3(const float* __restrict__ wc3){
  __shared__ float ws[64*120];
  int tid = threadIdx.x;
  int ec = blockIdx.x >> 7;
  int p = ((blockIdx.x & 127) << 8) + tid;
  const float* wsrc = wc3 + (size_t)ec*64*120;
  for (int i=tid;i<7680;i+=256) ws[i]=wsrc[i];
  __syncthreads();
  float x[120];
  xrow(p, 0, 120, x);
  for (int ei=0; ei<64; ei++){
    float y=0.f;
    #pragma unroll
    for (int c=0;c<120;c++) y = fmaf(ws[ei*120+c], x[c], y);
    g_e1[(size_t)(ec*64+ei)*PP + p] = y;
  }
}

// ==== c3 max over N ====
__global__ __launch_bounds__(256) void k_max3s(){
  __shared__ float red[256];
  int e = blockIdx.x >> 4;
  int b = blockIdx.x & 15;
  int t = threadIdx.x;
  float A = g_st[S3A+e], Bv = g_st[S3B+e];
  const float* src = g_e1 + (size_t)e*PP + b*NN;
  float mx = NEG_BIG;
  for (int i=t;i<NN;i+=256) mx = fmaxf(mx, lrelu(fmaf(A, src[i], Bv)));
  red[t]=mx; __syncthreads();
  for (int w=128;w>0;w>>=1){ if (t<w) red[t]=fmaxf(red[t],red[t+w]); __syncthreads(); }
  if (t==0) g_gsf[b*1024+e] = red[0];
}

// ---------------- VAE head
__global__ __launch_bounds__(256) void k_head(const float* __restrict__ eps,
                                              const float* __restrict__ wmu, const float* __restrict__ bmu,
                                              const float* __restrict__ wvar, const float* __restrict__ bvar,
                                              float* __restrict__ outb){
  int b = blockIdx.x, j = threadIdx.x;
  __shared__ float gs[1024];
  for (int i=j;i<1024;i+=256) gs[i] = g_gsf[b*1024+i];
  __syncthreads();
  float mu = bmu[j], lv = bvar[j];
  const float4* wm = (const float4*)(wmu + (size_t)j*1024);
  const float4* wv = (const float4*)(wvar + (size_t)j*1024);
  #pragma unroll 4
  for (int e=0;e<256;e++){
    float4 a = wm[e], c = wv[e];
    const float* g4 = gs + e*4;
    mu = fmaf(a.x,g4[0], fmaf(a.y,g4[1], fmaf(a.z,g4[2], fmaf(a.w,g4[3], mu))));
    lv = fmaf(c.x,g4[0], fmaf(c.y,g4[1], fmaf(c.z,g4[2], fmaf(c.w,g4[3], lv))));
  }
  float z = fmaf(eps[b*256+j], expf(0.5f*lv), mu);
  g_zf[b*256+j] = z;
  outb[O_MU + b*256 + j] = mu;
  outb[O_LV + b*256 + j] = lv;
  outb[O_Z  + b*256 + j] = z;
}

// ---------------- cuboid branch
__global__ __launch_bounds__(256) void k_cuboid(const float* __restrict__ wenc,
                                                const float* __restrict__ wcub1, const float* __restrict__ wcub2,
                                                const float* __restrict__ wk, float* __restrict__ outb){
  int b = blockIdx.x, t = threadIdx.x;
  __shared__ float xc[320*16];
  __shared__ float hh[256*16];
  __shared__ float xq[120*16];
  for (int i=t;i<320*16;i+=256){
    int c = i>>4, m = i&15;
    xc[i] = (c<256) ? g_zf[b*256+c] : lrelu(wenc[(c-256)*16+m]);
  }
  __syncthreads();
  {
    float acc[16];
    #pragma unroll
    for (int m=0;m<16;m++) acc[m]=0.f;
    for (int c=0;c<320;c++){
      float wv = wcub1[(size_t)t*320+c];
      #pragma unroll
      for (int m=0;m<16;m++) acc[m] = fmaf(wv, xc[c*16+m], acc[m]);
    }
    #pragma unroll
    for (int m=0;m<16;m++) hh[t*16+m] = lrelu(acc[m]);
  }
  __syncthreads();
  if (t<120){
    float a2[16];
    #pragma unroll
    for (int m=0;m<16;m++) a2[m]=0.f;
    for (int c=0;c<256;c++){
      float wv = wcub2[(size_t)t*256+c];
      #pragma unroll
      for (int m=0;m<16;m++) a2[m] = fmaf(wv, hh[c*16+m], a2[m]);
    }
    #pragma unroll
    for (int m=0;m<16;m++){
      float v = lrelu(a2[m]);
      xq[t*16+m] = v;
      outb[O_XCUB + b*1920 + t*16 + m] = v;
    }
  }
  __syncthreads();
  if (t<64){
    float a3[16];
    #pragma unroll
    for (int m=0;m<16;m++) a3[m]=0.f;
    for (int c=0;c<120;c++){
      float wv = wk[t*120+c];
      #pragma unroll
      for (int m=0;m<16;m++) a3[m] = fmaf(wv, xq[c*16+m], a3[m]);
    }
    #pragma unroll
    for (int m=0;m<16;m++) g_Kf[b*1024 + t*16 + m] = a3[m];
  }
}

// ---------------- attention
__global__ __launch_bounds__(64) void k_attn(const float* __restrict__ wq, float* __restrict__ outb){
  int p = blockIdx.x*64 + threadIdx.x;
  int b = p >> 11;
  float x[120];
  xrow(p, 0, 120, x);
  float sc[16];
  #pragma unroll
  for (int m=0;m<16;m++) sc[m]=0.f;
  for (int a=0;a<64;a++){
    float q=0.f;
    #pragma unroll
    for (int c=0;c<120;c++) q = fmaf(wq[a*120+c], x[c], q);
    q *= 0.125f;
    const float* kf = g_Kf + b*1024 + a*16;
    #pragma unroll
    for (int m=0;m<16;m++) sc[m] = fmaf(kf[m], q, sc[m]);
  }
  float mx = sc[0];
  #pragma unroll
  for (int m=1;m<16;m++) mx = fmaxf(mx, sc[m]);
  float s=0.f;
  #pragma unroll
  for (int m=0;m<16;m++){ sc[m] = expf(sc[m]-mx); s += sc[m]; }
  float inv = 1.f/s;
  #pragma unroll
  for (int m=0;m<16;m++) outb[O_ASG + (size_t)p*16 + m] = sc[m]*inv;
}

extern "C" void kernel_launch(void* const* d_in, const int* in_sizes, int n_in,
                              void* d_out, int out_size, void* d_ws, size_t ws_size,
                              hipStream_t stream){
  const float* xyz  = (const float*)d_in[0];
  const float* eps  = (const float*)d_in[2];
  const float* w1a  = (const float*)d_in[3];
  const float* w1b  = (const float*)d_in[4];
  const float* w2a  = (const float*)d_in[5];
  const float* w2b  = (const float*)d_in[6];
  const float* wc3  = (const float*)d_in[7];
  const float* wmu  = (const float*)d_in[8];
  const float* bmu  = (const float*)d_in[9];
  const float* wvar = (const float*)d_in[10];
  const float* bvar = (const float*)d_in[11];
  const float* wenc = (const float*)d_in[12];
  const float* wcub1= (const float*)d_in[13];
  const float* wcub2= (const float*)d_in[14];
  const float* wq   = (const float*)d_in[15];
  const float* wk   = (const float*)d_in[16];
  const float* g1a  = (const float*)d_in[17];
  const float* b1a  = (const float*)d_in[18];
  const float* g1b  = (const float*)d_in[19];
  const float* b1b  = (const float*)d_in[20];
  const float* g2a  = (const float*)d_in[21];
  const float* b2a  = (const float*)d_in[22];
  const float* g2b  = (const float*)d_in[23];
  const float* b2b  = (const float*)d_in[24];
  const float* g3   = (const float*)d_in[25];
  const float* b3   = (const float*)d_in[26];
  float* outb = (float*)d_out;

  const double inv1 = 1.0/(double)EE;
  const double inv3 = 1.0/(double)PP;

  // kNN (exact set selection)
  k_knnt<<<2048,128,0,stream>>>(xyz);
  k_knnu<<<128,256,0,stream>>>();
  k_knns1<<<1024,256,0,stream>>>(xyz);
  k_knns2<<<128,256,0,stream>>>();
  k_knns3<<<1024,256,0,stream>>>(xyz);
  // stage 1
  k_conv1a<<<2560,256,0,stream>>>(xyz, w1a);
  k_sstat<<<480,256,0,stream>>>(1, 8, EE/8);
  k_finS<<<1,64,0,stream>>>(g1a, b1a, S1A_AB, 8, inv1);
  k_conv1b<<<2560,256,0,stream>>>(w1b);
  k_sstat<<<480,256,0,stream>>>(0, 8, EE/8);
  k_finS<<<1,64,0,stream>>>(g1b, b1b, S1B_AB, 8, inv1);
  k_final1s<<<7680,256,0,stream>>>(outb);
  // stage 2
  k_pgem2<<<128,256,0,stream>>>(w2a);
  k_conv2a<<<2560,256,0,stream>>>();
  k_sstat<<<480,256,0,stream>>>(0, 8, EE/8);
  k_finS<<<1,64,0,stream>>>(g2a, b2a, S2A_AB, 8, inv1);
  k_conv2b<<<2560,256,0,stream>>>(w2b);
  k_sstat<<<480,256,0,stream>>>(1, 8, EE/8);
  k_finS<<<1,64,0,stream>>>(g2b, b2b, S2B_AB, 8, inv1);
  k_final2s<<<7680,256,0,stream>>>(outb);
  // stage 3
  k_conv3<<<2048,256,0,stream>>>(wc3);
  k_sstat<<<4096,256,0,stream>>>(0, 4, PP/4);
  k_fin3S<<<16,64,0,stream>>>(g3, b3, inv3);
  k_max3s<<<16384,256,0,stream>>>();
  // heads
  k_head<<<16,256,0,stream>>>(eps, wmu, bmu, wvar, bvar, outb);
  k_cuboid<<<16,256,0,stream>>>(wenc, wcub1, wcub2, wk, outb);
  k_attn<<<512,64,0,stream>>>(wq, outb);
}

// Round 21
// 1503.905 us; speedup vs baseline: 3.9196x; 3.9196x over previous
//
#include <hip/hip_runtime.h>

typedef unsigned int u32;
typedef unsigned short u16;

// problem sizes
#define BB 16
#define NN 2048
#define KK 20
#define EE (BB*NN*KK)      // 655360 edges
#define PP (BB*NN)         // 32768 points
#define NCHK 8             // kNN candidate chunks
#define CHKSZ (NN/NCHK)    // 256 candidates per chunk

// output element offsets (fp32 elements, tuple flattened in return order)
#define O_XPER 0
#define O_XCUB 3932160
#define O_Z    3962880
#define O_MU   3966976
#define O_LV   3971072
#define O_ASG  3975168

// ---- static device scratch: all write-before-read each call, no atomics ----
__device__ double g_part[4096*128];           // stats partials / kNN counters (4 MB)
__device__ double g_std[2560];                // reduced double sums
__device__ float  g_st[2560];                 // BN A/B per stage + stage3 A/B
__device__ float  g_gsf[BB*1024];             // global max g (B,1024)
__device__ float  g_zf[BB*256];               // z
__device__ float  g_Kf[BB*1024];              // Kf (B,64,16)
__device__ u16    g_idx[EE];                  // kNN indices
__device__ float  g_xpf[(size_t)PP*120];      // point-major x_per mirror (15.7 MB)
__device__ float  g_e1[(size_t)EE*60];        // knn chunk-tops -> y1a -> y2a -> y3
__device__ float  g_e2[(size_t)EE*60];        // knn T -> y1b -> U/V -> y2b

// double-sum bases in g_std: per 60-ch stage {sum@+0, sq@+64}
#define S1A_D 0
#define S1B_D 128
#define S2A_D 256
#define S2B_D 384
#define S3S_D 512
#define S3Q_D 1536
// A/B bases in g_st: per 60-ch stage {A@+0, B@+64}
#define S1A_AB 0
#define S1B_AB 128
#define S2A_AB 256
#define S2B_AB 384
#define S3A 512
#define S3B 1536

#define NEG_BIG -1.0e30f

__device__ __forceinline__ float lrelu(float x){ return x > 0.f ? x : 0.2f*x; }

__device__ __forceinline__ void xrow(int bn, int c0, int cnt, float* d){
  const float* s = g_xpf + (size_t)bn*120 + c0;
  #pragma unroll 4
  for (int i=0;i<cnt;i+=4){
    float4 v = *(const float4*)(s+i);
    d[i]=v.x; d[i+1]=v.y; d[i+2]=v.z; d[i+3]=v.w;
  }
}

// shared pd computation: MUST be bit-identical across all kNN kernels
__device__ __forceinline__ float pdcalc(float4 pm, float qx, float qy, float qz, float qw){
  float dot = fmaf(qx,pm.x, fmaf(qy,pm.y, qz*pm.z));
  float t = fmaf(2.f, dot, -qw);
  return t - pm.w;                      // == -||q-p||^2
}

// ---- float-only top-20 chain (distances only; 2 VALU ops per stage)
#define KT_DECL \
  float td0=NEG_BIG,td1=NEG_BIG,td2=NEG_BIG,td3=NEG_BIG,td4=NEG_BIG, \
        td5=NEG_BIG,td6=NEG_BIG,td7=NEG_BIG,td8=NEG_BIG,td9=NEG_BIG, \
        td10=NEG_BIG,td11=NEG_BIG,td12=NEG_BIG,td13=NEG_BIG,td14=NEG_BIG, \
        td15=NEG_BIG,td16=NEG_BIG,td17=NEG_BIG,td18=NEG_BIG,td19=NEG_BIG;
#define KT_CSW(u,l) { float mx = fmaxf(td##u, td##l); float mn = fminf(td##u, td##l); td##u = mx; td##l = mn; }
#define KT_INSERT(pd) \
  if ((pd) > td19){ \
    td19 = (pd); \
    KT_CSW(18,19) KT_CSW(17,18) KT_CSW(16,17) KT_CSW(15,16) \
    KT_CSW(14,15) KT_CSW(13,14) KT_CSW(12,13) KT_CSW(11,12) \
    KT_CSW(10,11) KT_CSW(9,10)  KT_CSW(8,9)   KT_CSW(7,8)   \
    KT_CSW(6,7)   KT_CSW(5,6)   KT_CSW(4,5)   KT_CSW(3,4)   \
    KT_CSW(2,3)   KT_CSW(1,2)   KT_CSW(0,1) }

// ---------------- kNN pass 1
__global__ __launch_bounds__(128) void k_knnt(const float* __restrict__ xyz){
  __shared__ float4 cand[CHKSZ];
  int qg = blockIdx.x >> 3;
  int c  = blockIdx.x & 7;
  int b  = qg >> 4;
  int n0 = (qg & 15) << 7;
  int t  = threadIdx.x;
  int m0 = c*CHKSZ;
  for (int i=t;i<CHKSZ;i+=128){
    const float* s = xyz + ((size_t)((b<<11)+m0+i))*3;
    float x=s[0], y=s[1], z=s[2];
    cand[i] = make_float4(x,y,z, fmaf(x,x,fmaf(y,y,z*z)));
  }
  __syncthreads();
  int n = n0 + t;
  const float* qs = xyz + ((size_t)((b<<11)+n))*3;
  float qx=qs[0], qy=qs[1], qz=qs[2];
  float qw = fmaf(qx,qx,fmaf(qy,qy,qz*qz));
  KT_DECL
  for (int i=0;i<CHKSZ;i++){
    float pd = pdcalc(cand[i], qx,qy,qz,qw);
    KT_INSERT(pd)
  }
  int p = (b<<11) + n;
  float* outd = g_e1;
  #define KOUT(k) outd[(size_t)(c*KK+k)*PP + p] = td##k;
  KOUT(0) KOUT(1) KOUT(2) KOUT(3) KOUT(4) KOUT(5) KOUT(6) KOUT(7) KOUT(8) KOUT(9)
  KOUT(10) KOUT(11) KOUT(12) KOUT(13) KOUT(14) KOUT(15) KOUT(16) KOUT(17) KOUT(18) KOUT(19)
  #undef KOUT
}

// ---------------- kNN pass 2: exact 20th-largest threshold T[q]
__global__ __launch_bounds__(256) void k_knnu(){
  int q = blockIdx.x*256 + threadIdx.x;
  const float* ind = g_e1;
  KT_DECL
  for (int i=0;i<NCHK*KK;i++){
    float pd = ind[(size_t)i*PP + q];
    KT_INSERT(pd)
  }
  g_e2[q] = td19;
}

// ---------------- kNN pass 3: count pd>T, pd==T per (query, chunk)
__global__ __launch_bounds__(256) void k_knns1(const float* __restrict__ xyz){
  __shared__ float4 cand[CHKSZ];
  int gid = blockIdx.x*256 + threadIdx.x;
  int c = gid >> 15;
  int q = gid & (PP-1);
  int b = q >> 11;
  int t = threadIdx.x;
  for (int i=t;i<CHKSZ;i+=256){
    const float* s = xyz + ((size_t)((b<<11)+c*CHKSZ+i))*3;
    float x=s[0], y=s[1], z=s[2];
    cand[i] = make_float4(x,y,z, fmaf(x,x,fmaf(y,y,z*z)));
  }
  __syncthreads();
  const float* qs = xyz + (size_t)q*3;
  float qx=qs[0], qy=qs[1], qz=qs[2];
  float qw = fmaf(qx,qx,fmaf(qy,qy,qz*qz));
  float T = g_e2[q];
  u32 cgt=0, ceq=0;
  for (int i=0;i<CHKSZ;i++){
    float pd = pdcalc(cand[i], qx,qy,qz,qw);
    cgt += (pd > T) ? 1u : 0u;
    ceq += (pd == T) ? 1u : 0u;
  }
  u32* cntg = (u32*)g_part;
  u32* cnte = cntg + NCHK*PP;
  cntg[c*PP + q] = cgt;
  cnte[c*PP + q] = ceq;
}

// ---------------- kNN pass 4: prefix over chunks
__global__ __launch_bounds__(256) void k_knns2(){
  int q = blockIdx.x*256 + threadIdx.x;
  u32* cntg = (u32*)g_part;
  u32* cnte = cntg + NCHK*PP;
  u32* bg   = cnte + NCHK*PP;
  u32* be   = bg   + NCHK*PP;
  u32 acc = 0;
  for (int c=0;c<NCHK;c++){ bg[c*PP+q] = acc; acc += cntg[c*PP+q]; }
  u32 eacc = acc;
  for (int c=0;c<NCHK;c++){ be[c*PP+q] = eacc; eacc += cnte[c*PP+q]; }
}

// ---------------- kNN pass 5: write indices
__global__ __launch_bounds__(256) void k_knns3(const float* __restrict__ xyz){
  __shared__ float4 cand[CHKSZ];
  int gid = blockIdx.x*256 + threadIdx.x;
  int c = gid >> 15;
  int q = gid & (PP-1);
  int b = q >> 11;
  int t = threadIdx.x;
  for (int i=t;i<CHKSZ;i+=256){
    const float* s = xyz + ((size_t)((b<<11)+c*CHKSZ+i))*3;
    float x=s[0], y=s[1], z=s[2];
    cand[i] = make_float4(x,y,z, fmaf(x,x,fmaf(y,y,z*z)));
  }
  __syncthreads();
  const float* qs = xyz + (size_t)q*3;
  float qx=qs[0], qy=qs[1], qz=qs[2];
  float qw = fmaf(qx,qx,fmaf(qy,qy,qz*qz));
  float T = g_e2[q];
  const u32* cntg = (const u32*)g_part;
  const u32* cnte = cntg + NCHK*PP;
  const u32* bg   = cnte + NCHK*PP;
  const u32* be   = bg   + NCHK*PP;
  u32 wgt = bg[c*PP+q];
  u32 weq = be[c*PP+q];
  u16* o = g_idx + (size_t)q*KK;
  for (int i=0;i<CHKSZ;i++){
    float pd = pdcalc(cand[i], qx,qy,qz,qw);
    int m = c*CHKSZ + i;
    if (pd > T && wgt < KK){ o[wgt] = (u16)m; wgt++; }
    else if (pd == T && weq < KK){ o[weq] = (u16)m; weq++; }
  }
}

// ---------------- reduce per-block double partials into g_std[dbase..] (nblk blocks)
__global__ __launch_bounds__(256) void k_red60(int dbase, int nblk){
  __shared__ double red[256];
  int s = blockIdx.x;                   // slot 0..127
  int t = threadIdx.x;
  double acc = 0.0;
  for (int i=t;i<nblk;i+=256) acc += g_part[(size_t)i*128 + s];
  red[t] = acc; __syncthreads();
  for (int w=128; w>0; w>>=1){ if (t<w) red[t]+=red[t+w]; __syncthreads(); }
  if (t==0) g_std[dbase+s] = red[0];
}

// ---------------- BN finalize in double
__global__ __launch_bounds__(64) void k_fin(const float* __restrict__ g, const float* __restrict__ bb,
                                            int dbase, int abase, double invc){
  int c = threadIdx.x;
  if (c < 60){
    double m = g_std[dbase+c]*invc;
    double v = g_std[dbase+64+c]*invc - m*m;
    if (v < 0.0) v = 0.0;
    float r = (float)(1.0/sqrt(v + 1e-5));
    float a = r*g[c];
    g_st[abase+c] = a;
    g_st[abase+64+c] = bb[c] - (float)m*a;
  }
}
__global__ __launch_bounds__(64) void k_fin3(const float* __restrict__ g, const float* __restrict__ bb, double invc){
  int c = blockIdx.x*64 + threadIdx.x;
  double m = g_std[S3S_D+c]*invc;
  double v = g_std[S3Q_D+c]*invc - m*m;
  if (v < 0.0) v = 0.0;
  float r = (float)(1.0/sqrt(v + 1e-5));
  float a = r*g[c];
  g_st[S3A+c] = a;
  g_st[S3B+c] = bb[c] - (float)m*a;
}

// ==== stage1 conv-a: y1a[o][edge] -> g_e1 + stats.  2560 blocks x 256 thr ====
__global__ __launch_bounds__(256) void k_conv1a(const float* __restrict__ xyz, const float* __restrict__ w1a){
  __shared__ float ws[360];
  __shared__ double sred[512];
  int tid = threadIdx.x, lane = tid & 63, wv = tid >> 6;
  for (int i=tid;i<360;i+=256) ws[i]=w1a[i];
  __syncthreads();
  int edge = blockIdx.x*256 + tid;
  int row = edge / KK;
  int b = row >> 11;
  int nbr = g_idx[edge];
  const float* cp = xyz + (size_t)row*3;
  const float* np2 = xyz + ((size_t)((b<<11)+nbr))*3;
  float c0=cp[0], c1=cp[1], c2=cp[2];
  float d0=np2[0]-c0, d1=np2[1]-c1, d2=np2[2]-c2;
  double rs=0.0, rq=0.0;
  for (int o=0;o<60;o++){
    float y = ws[o*6]*d0 + ws[o*6+1]*d1 + ws[o*6+2]*d2 + ws[o*6+3]*c0 + ws[o*6+4]*c1 + ws[o*6+5]*c2;
    g_e1[(size_t)o*EE + edge] = y;
    float s=y, q=y*y;
    #pragma unroll
    for (int m=1;m<64;m<<=1){ s += __shfl_xor(s,m); q += __shfl_xor(q,m); }
    if (lane==o){ rs += (double)s; rq += (double)q; }
  }
  sred[wv*128 + lane] = rs;
  sred[wv*128 + 64 + lane] = rq;
  __syncthreads();
  if (tid < 128)
    g_part[(size_t)blockIdx.x*128 + tid] = sred[tid] + sred[128+tid] + sred[256+tid] + sred[384+tid];
}

// ==== stage1 conv-b: h1 = lrelu(affine(y1a)); y1b = w1b.h1 -> g_e2 + stats ====
__global__ __launch_bounds__(256) void k_conv1b(const float* __restrict__ w1b){
  __shared__ float wbs[3600];
  __shared__ float As[60], Bs[60];
  __shared__ double sred[512];
  int tid = threadIdx.x, lane = tid & 63, wv = tid >> 6;
  for (int i=tid;i<3600;i+=256) wbs[i]=w1b[i];
  if (tid<60){ As[tid]=g_st[S1A_AB+tid]; Bs[tid]=g_st[S1A_AB+64+tid]; }
  __syncthreads();
  int edge = blockIdx.x*256 + tid;
  float h[60];
  #pragma unroll 4
  for (int o=0;o<60;o++) h[o] = lrelu(fmaf(As[o], g_e1[(size_t)o*EE + edge], Bs[o]));
  double rs=0.0, rq=0.0;
  for (int o=0;o<60;o++){
    float y=0.f;
    #pragma unroll
    for (int c=0;c<60;c++) y = fmaf(wbs[o*60+c], h[c], y);
    g_e2[(size_t)o*EE + edge] = y;
    float s=y, q=y*y;
    #pragma unroll
    for (int m=1;m<64;m<<=1){ s += __shfl_xor(s,m); q += __shfl_xor(q,m); }
    if (lane==o){ rs += (double)s; rq += (double)q; }
  }
  sred[wv*128 + lane] = rs;
  sred[wv*128 + 64 + lane] = rq;
  __syncthreads();
  if (tid < 128)
    g_part[(size_t)blockIdx.x*128 + tid] = sred[tid] + sred[128+tid] + sred[256+tid] + sred[384+tid];
}

// ==== stage1 final: x1[bn][o] = max_k lrelu(affine(y1b)).  60x128 blocks ====
__global__ __launch_bounds__(256) void k_final1s(float* __restrict__ outb){
  int o = blockIdx.x >> 7;
  int bn = ((blockIdx.x & 127) << 8) + threadIdx.x;
  int b = bn >> 11, n = bn & 2047;
  float A = g_st[S1B_AB+o], Bv = g_st[S1B_AB+64+o];
  const float* src = g_e2 + (size_t)o*EE + (size_t)bn*KK;
  float mx = NEG_BIG;
  #pragma unroll
  for (int k=0;k<KK;k++) mx = fmaxf(mx, lrelu(fmaf(A, src[k], Bv)));
  g_xpf[(size_t)bn*120 + o] = mx;
  outb[O_XPER + (size_t)(b*120+o)*NN + n] = mx;
}

// ==== stage2 point transforms: U = Wd.x1, V = (Wc-Wd).x1 -> g_e2 [p][64] ====
__global__ __launch_bounds__(256) void k_pgem2(const float* __restrict__ w2a){
  __shared__ float wd[3600], wcd[3600];
  int tid = threadIdx.x;
  for (int i=tid;i<3600;i+=256){
    int o = i/60, c = i%60;
    float a = w2a[o*120+c], bvl = w2a[o*120+60+c];
    wd[i] = a; wcd[i] = bvl - a;
  }
  __syncthreads();
  int p = blockIdx.x*256 + tid;
  float x[60];
  xrow(p, 0, 60, x);
  float* gU = g_e2;
  float* gV = g_e2 + (size_t)PP*64;
  #pragma unroll 4
  for (int o=0;o<60;o++){
    float u=0.f, v=0.f;
    #pragma unroll
    for (int c=0;c<60;c++){ u = fmaf(wd[o*60+c], x[c], u); v = fmaf(wcd[o*60+c], x[c], v); }
    gU[(size_t)p*64 + o] = u;
    gV[(size_t)p*64 + o] = v;
  }
}

// ==== stage2 conv-a: y2a = U[nbr] + V[center] -> g_e1 + butterfly stats ====
__global__ __launch_bounds__(256) void k_conv2a(){
  __shared__ double sred[512];
  int tid = threadIdx.x, lane = tid & 63, wv = tid >> 6;
  int edge = blockIdx.x*256 + tid;
  int row = edge / KK;
  int b = row >> 11;
  int nbr = g_idx[edge];
  int pn = (b<<11)+nbr;
  const float4* gU = (const float4*)g_e2;
  const float4* gV = (const float4*)(g_e2 + (size_t)PP*64);
  double rs=0.0, rq=0.0;
  #pragma unroll
  for (int o4=0;o4<15;o4++){
    float4 uu = gU[(size_t)pn*16 + o4];
    float4 vv = gV[(size_t)row*16 + o4];
    float y0=uu.x+vv.x, y1=uu.y+vv.y, y2=uu.z+vv.z, y3=uu.w+vv.w;
    g_e1[(size_t)(o4*4+0)*EE + edge] = y0;
    g_e1[(size_t)(o4*4+1)*EE + edge] = y1;
    g_e1[(size_t)(o4*4+2)*EE + edge] = y2;
    g_e1[(size_t)(o4*4+3)*EE + edge] = y3;
    float ys[4] = {y0,y1,y2,y3};
    #pragma unroll
    for (int j=0;j<4;j++){
      float s=ys[j], q=ys[j]*ys[j];
      #pragma unroll
      for (int m=1;m<64;m<<=1){ s += __shfl_xor(s,m); q += __shfl_xor(q,m); }
      if (lane==o4*4+j){ rs += (double)s; rq += (double)q; }
    }
  }
  sred[wv*128 + lane] = rs;
  sred[wv*128 + 64 + lane] = rq;
  __syncthreads();
  if (tid < 128)
    g_part[(size_t)blockIdx.x*128 + tid] = sred[tid] + sred[128+tid] + sred[256+tid] + sred[384+tid];
}

// ==== stage2 conv-b: h=lrelu(affine(y2a)); y2b=w2b.h -> g_e2 + stats ====
__global__ __launch_bounds__(256) void k_conv2b(const float* __restrict__ w2b){
  __shared__ float wbs[3600];
  __shared__ float As[60], Bs[60];
  __shared__ double sred[512];
  int tid = threadIdx.x, lane = tid & 63, wv = tid >> 6;
  for (int i=tid;i<3600;i+=256) wbs[i]=w2b[i];
  if (tid<60){ As[tid]=g_st[S2A_AB+tid]; Bs[tid]=g_st[S2A_AB+64+tid]; }
  __syncthreads();
  int edge = blockIdx.x*256 + tid;
  float h[60];
  #pragma unroll 4
  for (int o=0;o<60;o++) h[o] = lrelu(fmaf(As[o], g_e1[(size_t)o*EE + edge], Bs[o]));
  double rs=0.0, rq=0.0;
  for (int o=0;o<60;o++){
    float y=0.f;
    #pragma unroll
    for (int c=0;c<60;c++) y = fmaf(wbs[o*60+c], h[c], y);
    g_e2[(size_t)o*EE + edge] = y;
    float s=y, q=y*y;
    #pragma unroll
    for (int m=1;m<64;m<<=1){ s += __shfl_xor(s,m); q += __shfl_xor(q,m); }
    if (lane==o){ rs += (double)s; rq += (double)q; }
  }
  sred[wv*128 + lane] = rs;
  sred[wv*128 + 64 + lane] = rq;
  __syncthreads();
  if (tid < 128)
    g_part[(size_t)blockIdx.x*128 + tid] = sred[tid] + sred[128+tid] + sred[256+tid] + sred[384+tid];
}

// ==== stage2 final: x2 from g_e2 ====
__global__ __launch_bounds__(256) void k_final2s(float* __restrict__ outb){
  int o = blockIdx.x >> 7;
  int bn = ((blockIdx.x & 127) << 8) + threadIdx.x;
  int b = bn >> 11, n = bn & 2047;
  float A = g_st[S2B_AB+o], Bv = g_st[S2B_AB+64+o];
  const float* src = g_e2 + (size_t)o*EE + (size_t)bn*KK;
  float mx = NEG_BIG;
  #pragma unroll
  for (int k=0;k<KK;k++) mx = fmaxf(mx, lrelu(fmaf(A, src[k], Bv)));
  g_xpf[(size_t)bn*120 + 60 + o] = mx;
  outb[O_XPER + (size_t)(b*120+60+o)*NN + n] = mx;
}

// ==== c3: y3[e][point] -> g_e1 + stats ====
__global__ __launch_bounds__(256) void k_conv3(const float* __restrict__ wc3){
  __shared__ float ws[64*120];
  __shared__ double sred[512];
  int tid = threadIdx.x, lane = tid & 63, wv = tid >> 6;
  int ec = blockIdx.x >> 7;
  int p = ((blockIdx.x & 127) << 8) + tid;
  const float* wsrc = wc3 + (size_t)ec*64*120;
  for (int i=tid;i<7680;i+=256) ws[i]=wsrc[i];
  __syncthreads();
  float x[120];
  xrow(p, 0, 120, x);
  double rs=0.0, rq=0.0;
  for (int ei=0; ei<64; ei++){
    float y=0.f;
    #pragma unroll
    for (int c=0;c<120;c++) y = fmaf(ws[ei*120+c], x[c], y);
    g_e1[(size_t)(ec*64+ei)*PP + p] = y;
    float s=y, q=y*y;
    #pragma unroll
    for (int m=1;m<64;m<<=1){ s += __shfl_xor(s,m); q += __shfl_xor(q,m); }
    if (lane==ei){ rs += (double)s; rq += (double)q; }
  }
  sred[wv*128 + lane] = rs;
  sred[wv*128 + 64 + lane] = rq;
  __syncthreads();
  if (tid < 128)
    g_part[(size_t)blockIdx.x*128 + tid] = sred[tid] + sred[128+tid] + sred[256+tid] + sred[384+tid];
}

// reduce stage-3 partials: block = channel e; 128 point-group partials
__global__ __launch_bounds__(256) void k_red3(){
  __shared__ double reds[256], redq[256];
  int e = blockIdx.x;
  int ec = e >> 6, ei = e & 63;
  int t = threadIdx.x;
  double accs=0.0, accq=0.0;
  for (int pg=t; pg<128; pg+=256){
    size_t base = (size_t)(ec*128+pg)*128;
    accs += g_part[base + ei];
    accq += g_part[base + 64 + ei];
  }
  reds[t]=accs; redq[t]=accq; __syncthreads();
  for (int w=128; w>0; w>>=1){ if (t<w){ reds[t]+=reds[t+w]; redq[t]+=redq[t+w]; } __syncthreads(); }
  if (t==0){ g_std[S3S_D+e]=reds[0]; g_std[S3Q_D+e]=redq[0]; }
}

// ==== c3 max over N ====
__global__ __launch_bounds__(256) void k_max3s(){
  __shared__ float red[256];
  int e = blockIdx.x >> 4;
  int b = blockIdx.x & 15;
  int t = threadIdx.x;
  float A = g_st[S3A+e], Bv = g_st[S3B+e];
  const float* src = g_e1 + (size_t)e*PP + b*NN;
  float mx = NEG_BIG;
  for (int i=t;i<NN;i+=256) mx = fmaxf(mx, lrelu(fmaf(A, src[i], Bv)));
  red[t]=mx; __syncthreads();
  for (int w=128;w>0;w>>=1){ if (t<w) red[t]=fmaxf(red[t],red[t+w]); __syncthreads(); }
  if (t==0) g_gsf[b*1024+e] = red[0];
}

// ---------------- VAE head
__global__ __launch_bounds__(256) void k_head(const float* __restrict__ eps,
                                              const float* __restrict__ wmu, const float* __restrict__ bmu,
                                              const float* __restrict__ wvar, const float* __restrict__ bvar,
                                              float* __restrict__ outb){
  int b = blockIdx.x, j = threadIdx.x;
  __shared__ float gs[1024];
  for (int i=j;i<1024;i+=256) gs[i] = g_gsf[b*1024+i];
  __syncthreads();
  float mu = bmu[j], lv = bvar[j];
  const float4* wm = (const float4*)(wmu + (size_t)j*1024);
  const float4* wv = (const float4*)(wvar + (size_t)j*1024);
  #pragma unroll 4
  for (int e=0;e<256;e++){
    float4 a = wm[e], c = wv[e];
    const float* g4 = gs + e*4;
    mu = fmaf(a.x,g4[0], fmaf(a.y,g4[1], fmaf(a.z,g4[2], fmaf(a.w,g4[3], mu))));
    lv = fmaf(c.x,g4[0], fmaf(c.y,g4[1], fmaf(c.z,g4[2], fmaf(c.w,g4[3], lv))));
  }
  float z = fmaf(eps[b*256+j], expf(0.5f*lv), mu);
  g_zf[b*256+j] = z;
  outb[O_MU + b*256 + j] = mu;
  outb[O_LV + b*256 + j] = lv;
  outb[O_Z  + b*256 + j] = z;
}

// ---------------- cuboid branch
__global__ __launch_bounds__(256) void k_cuboid(const float* __restrict__ wenc,
                                                const float* __restrict__ wcub1, const float* __restrict__ wcub2,
                                                const float* __restrict__ wk, float* __restrict__ outb){
  int b = blockIdx.x, t = threadIdx.x;
  __shared__ float xc[320*16];
  __shared__ float hh[256*16];
  __shared__ float xq[120*16];
  for (int i=t;i<320*16;i+=256){
    int c = i>>4, m = i&15;
    xc[i] = (c<256) ? g_zf[b*256+c] : lrelu(wenc[(c-256)*16+m]);
  }
  __syncthreads();
  {
    float acc[16];
    #pragma unroll
    for (int m=0;m<16;m++) acc[m]=0.f;
    for (int c=0;c<320;c++){
      float wv = wcub1[(size_t)t*320+c];
      #pragma unroll
      for (int m=0;m<16;m++) acc[m] = fmaf(wv, xc[c*16+m], acc[m]);
    }
    #pragma unroll
    for (int m=0;m<16;m++) hh[t*16+m] = lrelu(acc[m]);
  }
  __syncthreads();
  if (t<120){
    float a2[16];
    #pragma unroll
    for (int m=0;m<16;m++) a2[m]=0.f;
    for (int c=0;c<256;c++){
      float wv = wcub2[(size_t)t*256+c];
      #pragma unroll
      for (int m=0;m<16;m++) a2[m] = fmaf(wv, hh[c*16+m], a2[m]);
    }
    #pragma unroll
    for (int m=0;m<16;m++){
      float v = lrelu(a2[m]);
      xq[t*16+m] = v;
      outb[O_XCUB + b*1920 + t*16 + m] = v;
    }
  }
  __syncthreads();
  if (t<64){
    float a3[16];
    #pragma unroll
    for (int m=0;m<16;m++) a3[m]=0.f;
    for (int c=0;c<120;c++){
      float wv = wk[t*120+c];
      #pragma unroll
      for (int m=0;m<16;m++) a3[m] = fmaf(wv, xq[c*16+m], a3[m]);
    }
    #pragma unroll
    for (int m=0;m<16;m++) g_Kf[b*1024 + t*16 + m] = a3[m];
  }
}

// ---------------- attention
__global__ __launch_bounds__(64) void k_attn(const float* __restrict__ wq, float* __restrict__ outb){
  int p = blockIdx.x*64 + threadIdx.x;
  int b = p >> 11;
  float x[120];
  xrow(p, 0, 120, x);
  float sc[16];
  #pragma unroll
  for (int m=0;m<16;m++) sc[m]=0.f;
  for (int a=0;a<64;a++){
    float q=0.f;
    #pragma unroll
    for (int c=0;c<120;c++) q = fmaf(wq[a*120+c], x[c], q);
    q *= 0.125f;
    const float* kf = g_Kf + b*1024 + a*16;
    #pragma unroll
    for (int m=0;m<16;m++) sc[m] = fmaf(kf[m], q, sc[m]);
  }
  float mx = sc[0];
  #pragma unroll
  for (int m=1;m<16;m++) mx = fmaxf(mx, sc[m]);
  float s=0.f;
  #pragma unroll
  for (int m=0;m<16;m++){ sc[m] = expf(sc[m]-mx); s += sc[m]; }
  float inv = 1.f/s;
  #pragma unroll
  for (int m=0;m<16;m++) outb[O_ASG + (size_t)p*16 + m] = sc[m]*inv;
}

extern "C" void kernel_launch(void* const* d_in, const int* in_sizes, int n_in,
                              void* d_out, int out_size, void* d_ws, size_t ws_size,
                              hipStream_t stream){
  const float* xyz  = (const float*)d_in[0];
  const float* eps  = (const float*)d_in[2];
  const float* w1a  = (const float*)d_in[3];
  const float* w1b  = (const float*)d_in[4];
  const float* w2a  = (const float*)d_in[5];
  const float* w2b  = (const float*)d_in[6];
  const float* wc3  = (const float*)d_in[7];
  const float* wmu  = (const float*)d_in[8];
  const float* bmu  = (const float*)d_in[9];
  const float* wvar = (const float*)d_in[10];
  const float* bvar = (const float*)d_in[11];
  const float* wenc = (const float*)d_in[12];
  const float* wcub1= (const float*)d_in[13];
  const float* wcub2= (const float*)d_in[14];
  const float* wq   = (const float*)d_in[15];
  const float* wk   = (const float*)d_in[16];
  const float* g1a  = (const float*)d_in[17];
  const float* b1a  = (const float*)d_in[18];
  const float* g1b  = (const float*)d_in[19];
  const float* b1b  = (const float*)d_in[20];
  const float* g2a  = (const float*)d_in[21];
  const float* b2a  = (const float*)d_in[22];
  const float* g2b  = (const float*)d_in[23];
  const float* b2b  = (const float*)d_in[24];
  const float* g3   = (const float*)d_in[25];
  const float* b3   = (const float*)d_in[26];
  float* outb = (float*)d_out;

  const double inv1 = 1.0/(double)EE;
  const double inv3 = 1.0/(double)PP;

  k_knnt<<<2048,128,0,stream>>>(xyz);
  k_knnu<<<128,256,0,stream>>>();
  k_knns1<<<1024,256,0,stream>>>(xyz);
  k_knns2<<<128,256,0,stream>>>();
  k_knns3<<<1024,256,0,stream>>>(xyz);
  k_conv1a<<<2560,256,0,stream>>>(xyz, w1a);
  k_red60<<<128,256,0,stream>>>(S1A_D, 2560);
  k_fin<<<1,64,0,stream>>>(g1a, b1a, S1A_D, S1A_AB, inv1);
  k_conv1b<<<2560,256,0,stream>>>(w1b);
  k_red60<<<128,256,0,stream>>>(S1B_D, 2560);
  k_fin<<<1,64,0,stream>>>(g1b, b1b, S1B_D, S1B_AB, inv1);
  k_final1s<<<7680,256,0,stream>>>(outb);
  k_pgem2<<<128,256,0,stream>>>(w2a);
  k_conv2a<<<2560,256,0,stream>>>();
  k_red60<<<128,256,0,stream>>>(S2A_D, 2560);
  k_fin<<<1,64,0,stream>>>(g2a, b2a, S2A_D, S2A_AB, inv1);
  k_conv2b<<<2560,256,0,stream>>>(w2b);
  k_red60<<<128,256,0,stream>>>(S2B_D, 2560);
  k_fin<<<1,64,0,stream>>>(g2b, b2b, S2B_D, S2B_AB, inv1);
  k_final2s<<<7680,256,0,stream>>>(outb);
  k_conv3<<<2048,256,0,stream>>>(wc3);
  k_red3<<<1024,256,0,stream>>>();
  k_fin3<<<16,64,0,stream>>>(g3, b3, inv3);
  k_max3s<<<16384,256,0,stream>>>();
  k_head<<<16,256,0,stream>>>(eps, wmu, bmu, wvar, bvar, outb);
  k_cuboid<<<16,256,0,stream>>>(wenc, wcub1, wcub2, wk, outb);
  k_attn<<<512,64,0,stream>>>(wq, outb);
}